// Round 12
// baseline (31.242 us; speedup 1.0000x reference)
//
#include <hip/hip_runtime.h>
#include <hip/hip_bf16.h>

// Problem constants (fixed by setup_inputs):
//   x: (64, 8192) f32   weight: (8192, 2048) f32
//   random_numbers: (4,) int (int32 or int64 storage, values in [1, 2^20))
//   y: (64, 8192) f32
#define K_FULL   8192
#define M_ROWS   64
#define N_OUT    8192
#define N_COMP   2048
#define P_MERS   2147483647

// ws layout: [0, 256KB) : xcF bf16, fragment-major:
//   xcF[(s*4 + g)*512 + lane*8 + e] = xc[g*16 + (lane&15)][s*32 + (lane>>4)*8 + e]
//   (s = k-step 0..63, g = m-group 0..3) -> every A-fragment load is 64x16B contiguous.

typedef __attribute__((ext_vector_type(8))) short bf16x8;
typedef __attribute__((ext_vector_type(4))) float f32x4;

__device__ __forceinline__ short f2bfs(float f) {
    __hip_bfloat16 h = __float2bfloat16(f);
    return *reinterpret_cast<short*>(&h);
}
__device__ __forceinline__ unsigned int pk2bf(float a, float b) {
    return (unsigned int)(unsigned short)f2bfs(a)
         | ((unsigned int)(unsigned short)f2bfs(b) << 16);
}

__device__ __forceinline__ int hash_col(int j, int rn0, int rn1, int rn2, int rn3) {
    if (rn1 == 0 && rn3 == 0) {
        // int64 storage (JAX x64 on): exact hash; Mersenne fold (2^31 === 1 mod P)
        unsigned long long xx = (unsigned long long)(unsigned int)rn0 * (unsigned int)j
                              + (unsigned long long)(unsigned int)rn2;
        unsigned long long t = (xx & (unsigned long long)P_MERS) + (xx >> 31);
        if (t >= (unsigned long long)P_MERS) t -= (unsigned long long)P_MERS;
        return (int)(t & (N_COMP - 1));
    } else {
        // int32 storage (JAX x64 off): int32 wraparound + floored mod
        unsigned int t = (unsigned int)rn0 * (unsigned int)j + (unsigned int)rn1;
        int ti = (int)t;
        int m1 = ti % P_MERS;
        if (m1 < 0) m1 += P_MERS;
        return m1 & (N_COMP - 1);
    }
}

// Fused scatter+pack: block = one m row. LDS scatter-add, then pack bf16 into
// fragment-major xcF (scattered dword writes, 4KB/block -> negligible).
__global__ __launch_bounds__(1024) void k_xc(const float* __restrict__ x,
                                             const int* __restrict__ rn,
                                             unsigned int* __restrict__ xcF) {
    __shared__ float row[N_COMP];
    const int m = blockIdx.x;
    const int tid = threadIdx.x;
    row[tid] = 0.0f;
    row[tid + 1024] = 0.0f;
    const int rn0 = rn[0], rn1 = rn[1], rn2 = rn[2], rn3 = rn[3];
    __syncthreads();

    const float* xm = x + (size_t)m * K_FULL;
#pragma unroll
    for (int it = 0; it < 2; ++it) {
        int j0 = tid * 4 + it * 4096;
        float4 v = *(const float4*)(xm + j0);
        atomicAdd(&row[hash_col(j0 + 0, rn0, rn1, rn2, rn3)], v.x);
        atomicAdd(&row[hash_col(j0 + 1, rn0, rn1, rn2, rn3)], v.y);
        atomicAdd(&row[hash_col(j0 + 2, rn0, rn1, rn2, rn3)], v.z);
        atomicAdd(&row[hash_col(j0 + 3, rn0, rn1, rn2, rn3)], v.w);
    }
    __syncthreads();

    // pack c0=2*tid, c0+1 (same s,kg; adjacent e -> one dword)
    const int c0 = 2 * tid;
    const int s  = c0 >> 5;
    const int kg = (c0 >> 3) & 3;
    const int e0 = c0 & 7;
    const int g  = m >> 4;
    const int nr = m & 15;
    xcF[(((s * 4 + g) * 64 + kg * 16 + nr) << 2) + (e0 >> 1)] =
        pk2bf(row[c0], row[c0 + 1]);
}

// MFMA GEMM v8 = R3 structure (compiler-scheduled full unroll, no k-loop
// barriers, no staging) + fragment-major A (R8) + per-block k-rotation (R11).
// 512 blocks x 256 thr (4 waves). Block owns 16 n-cols; wave w owns the
// contiguous k-slice [w*512, (w+1)*512) = 16 k-steps, visited in rotated
// order sk = (s + rot) & 15 (rot = blockIdx & 15) to spread the chip's
// instantaneous W k-window across address classes. B-fragments per-lane
// direct from row-major W (f32 -> bf16 in-register); A-fragments contiguous
// 64x16B from L2-resident xcF. LDS reduce of 4 wave-partials at the end.
__global__ __launch_bounds__(256) void k_gemm(const float* __restrict__ W,
                                              const unsigned short* __restrict__ xcF,
                                              float* __restrict__ y) {
    __shared__ float ys[4][M_ROWS][16];  // 16 KB
    const int tid  = threadIdx.x;
    const int lane = tid & 63;
    const int w    = __builtin_amdgcn_readfirstlane(tid >> 6);  // wave 0..3
    const int nr   = lane & 15;
    const int kg   = lane >> 4;
    const int n0   = blockIdx.x * 16;
    const int rot  = blockIdx.x & 15;

    // B: row n0+nr, k = w*512 + sk*32 + kg*8 (+0..7)
    const float* wp = W + (size_t)(n0 + nr) * N_COMP + w * 512 + kg * 8;
    // A: global k-step s_g = w*16 + sk; shorts offset s_g*2048 + lane*8
    const unsigned short* ab = xcF + (size_t)w * 16 * 2048 + lane * 8;

    f32x4 acc0 = {0.f, 0.f, 0.f, 0.f};
    f32x4 acc1 = {0.f, 0.f, 0.f, 0.f};
    f32x4 acc2 = {0.f, 0.f, 0.f, 0.f};
    f32x4 acc3 = {0.f, 0.f, 0.f, 0.f};

#pragma unroll
    for (int s = 0; s < 16; ++s) {
        const int sk = (s + rot) & 15;
        float4 w0 = *(const float4*)(wp + sk * 32);
        float4 w1 = *(const float4*)(wp + sk * 32 + 4);
        const unsigned short* ap = ab + (size_t)sk * 2048;
        bf16x8 a0 = *(const bf16x8*)(ap);
        bf16x8 a1 = *(const bf16x8*)(ap + 512);
        bf16x8 a2 = *(const bf16x8*)(ap + 1024);
        bf16x8 a3 = *(const bf16x8*)(ap + 1536);
        bf16x8 b;
        b[0] = f2bfs(w0.x); b[1] = f2bfs(w0.y);
        b[2] = f2bfs(w0.z); b[3] = f2bfs(w0.w);
        b[4] = f2bfs(w1.x); b[5] = f2bfs(w1.y);
        b[6] = f2bfs(w1.z); b[7] = f2bfs(w1.w);
        acc0 = __builtin_amdgcn_mfma_f32_16x16x32_bf16(a0, b, acc0, 0, 0, 0);
        acc1 = __builtin_amdgcn_mfma_f32_16x16x32_bf16(a1, b, acc1, 0, 0, 0);
        acc2 = __builtin_amdgcn_mfma_f32_16x16x32_bf16(a2, b, acc2, 0, 0, 0);
        acc3 = __builtin_amdgcn_mfma_f32_16x16x32_bf16(a3, b, acc3, 0, 0, 0);
    }

    // C/D layout (m89-verified): col = lane&15, row = (lane>>4)*4 + j
#pragma unroll
    for (int j = 0; j < 4; ++j) {
        ys[w][ 0 + kg * 4 + j][nr] = acc0[j];
        ys[w][16 + kg * 4 + j][nr] = acc1[j];
        ys[w][32 + kg * 4 + j][nr] = acc2[j];
        ys[w][48 + kg * 4 + j][nr] = acc3[j];
    }
    __syncthreads();

    // reduce 4 wave-partials, direct store: 1024 outputs, 4 per thread
#pragma unroll
    for (int i = 0; i < 4; ++i) {
        int o = tid + 256 * i;
        int m = o >> 4;
        int n = o & 15;
        float s = ys[0][m][n] + ys[1][m][n] + ys[2][m][n] + ys[3][m][n];
        y[(size_t)m * N_OUT + n0 + n] = s;
    }
}

extern "C" void kernel_launch(void* const* d_in, const int* in_sizes, int n_in,
                              void* d_out, int out_size, void* d_ws, size_t ws_size,
                              hipStream_t stream) {
    const float* x = (const float*)d_in[0];
    const float* W = (const float*)d_in[1];
    const int* rn  = (const int*)d_in[2];
    float* y       = (float*)d_out;

    unsigned int* xcF = (unsigned int*)d_ws;

    k_xc<<<M_ROWS, 1024, 0, stream>>>(x, rn, xcF);
    k_gemm<<<N_OUT / 16, 256, 0, stream>>>(W, (const unsigned short*)xcF, y);
}